// Round 8
// baseline (561.179 us; speedup 1.0000x reference)
//
#include <hip/hip_runtime.h>

typedef __attribute__((ext_vector_type(8))) short s16x8;   // 8 bf16 (4 VGPRs)
typedef __attribute__((ext_vector_type(4))) float f32x4;   // MFMA 16x16 accumulator
typedef unsigned short u16;
typedef unsigned int u32;

#define MFMA(A, B, C) __builtin_amdgcn_mfma_f32_16x16x32_bf16(A, B, C, 0, 0, 0)

__device__ __forceinline__ u16 f2bf(float f) {
  u32 u = __builtin_bit_cast(u32, f);
  u += 0x7fffu + ((u >> 16) & 1u);   // RNE
  return (u16)(u >> 16);
}

// async global->LDS, 16B per lane. LDS dest = wave-uniform base + lane*16
// (m97 pattern: LDS layout must be linear in lane order; no padding).
__device__ __forceinline__ void gl2lds16(const void* g, void* l) {
  __builtin_amdgcn_global_load_lds(
      (const __attribute__((address_space(1))) void*)g,
      (__attribute__((address_space(3))) void*)l, 16, 0, 0);
}

// ---------------- conversions ----------------

// fp32 -> bf16, 8 elems/thread, n8 = n/8
__global__ __launch_bounds__(256) void cvt_f32_bf16(const float* __restrict__ in,
                                                    u16* __restrict__ out, int n8) {
  int i = blockIdx.x * 256 + threadIdx.x;
  if (i >= n8) return;
  const float4* p = (const float4*)in + (size_t)i * 2;
  float4 a = p[0], b = p[1];
  union { u16 h[8]; uint4 v; } u;
  u.h[0] = f2bf(a.x); u.h[1] = f2bf(a.y); u.h[2] = f2bf(a.z); u.h[3] = f2bf(a.w);
  u.h[4] = f2bf(b.x); u.h[5] = f2bf(b.y); u.h[6] = f2bf(b.z); u.h[7] = f2bf(b.w);
  ((uint4*)out)[i] = u.v;
}

// in [R][C] fp32 -> out [C][R] bf16 (tiled transpose). R,C multiples of 32.
__global__ __launch_bounds__(256) void transpose_cvt(const float* __restrict__ in,
                                                     u16* __restrict__ out, int R, int C) {
  __shared__ float tile[32][33];
  int c0 = blockIdx.x * 32, r0 = blockIdx.y * 32;
  int tx = threadIdx.x, ty = threadIdx.y;
  #pragma unroll
  for (int i = ty; i < 32; i += 8)
    tile[i][tx] = in[(size_t)(r0 + i) * C + c0 + tx];
  __syncthreads();
  #pragma unroll
  for (int i = ty; i < 32; i += 8)
    out[(size_t)(c0 + i) * R + r0 + tx] = f2bf(tile[tx][i]);
}

// ---------------- GEMM: C[M][N] = A[M][K] @ Bt[N][K]^T ----------------
// 128x128 tile, BK=64, 256 threads = 4 waves in 2x2, each wave 64x64 (4x4 frags).
// Staging via global_load_lds width=16 (m97): linear LDS [128][64], each wave
// issues 4x 1KB per operand; lane l of issue covers row base+(l>>3), col (l&7)*8.
// BF16_OUT=1: write bf16. BF16_OUT=0: write fp32 + bias[col].
template <int BF16_OUT>
__global__ __launch_bounds__(256, 2) void gemm_bt(
    const u16* __restrict__ A, const u16* __restrict__ Bt,
    u16* __restrict__ Cb, float* __restrict__ Cf, const float* __restrict__ bias,
    int M, int N, int K) {
  __shared__ u16 alds[128][64];   // 16 KB, LINEAR (row = 128B) — required by global_load_lds
  __shared__ u16 blds[128][64];   // 16 KB
  const int tid = threadIdx.x;
  const int lane = tid & 63, wid = tid >> 6;
  const int wm = (wid >> 1) * 64, wn = (wid & 1) * 64;
  const int m0 = blockIdx.y * 128, n0 = blockIdx.x * 128;

  // per-lane source offsets for staging (match linear LDS lane order exactly)
  const int srow = lane >> 3;        // 0..7
  const int scol = (lane & 7) * 8;   // 0..56

  f32x4 acc[4][4];
  #pragma unroll
  for (int m = 0; m < 4; m++)
    #pragma unroll
    for (int n = 0; n < 4; n++) acc[m][n] = {0.f, 0.f, 0.f, 0.f};

  for (int k0 = 0; k0 < K; k0 += 64) {
    __syncthreads();
    #pragma unroll
    for (int i = 0; i < 4; i++) {
      int rbase = (wid * 4 + i) * 8;             // wave-uniform LDS row base
      int grow = rbase + srow;
      gl2lds16(&A [(size_t)(m0 + grow) * K + k0 + scol], &alds[rbase][0]);
      gl2lds16(&Bt[(size_t)(n0 + grow) * K + k0 + scol], &blds[rbase][0]);
    }
    __syncthreads();   // compiler emits s_waitcnt vmcnt(0) before s_barrier -> loads complete
    #pragma unroll
    for (int kk = 0; kk < 2; kk++) {
      s16x8 af[4], bf[4];
      #pragma unroll
      for (int m = 0; m < 4; m++)
        af[m] = *(const s16x8*)&alds[wm + m * 16 + (lane & 15)][kk * 32 + (lane >> 4) * 8];
      #pragma unroll
      for (int n = 0; n < 4; n++)
        bf[n] = *(const s16x8*)&blds[wn + n * 16 + (lane & 15)][kk * 32 + (lane >> 4) * 8];
      #pragma unroll
      for (int m = 0; m < 4; m++)
        #pragma unroll
        for (int n = 0; n < 4; n++)
          acc[m][n] = MFMA(af[m], bf[n], acc[m][n]);
    }
  }

  #pragma unroll
  for (int m = 0; m < 4; m++)
    #pragma unroll
    for (int n = 0; n < 4; n++) {
      int col = n0 + wn + n * 16 + (lane & 15);
      #pragma unroll
      for (int r = 0; r < 4; r++) {
        int row = m0 + wm + m * 16 + (lane >> 4) * 4 + r;
        float v = acc[m][n][r];
        if (BF16_OUT) Cb[(size_t)row * N + col] = f2bf(v);
        else          Cf[(size_t)row * N + col] = v + bias[col];
      }
    }
}

// ---------------- Flash attention (causal), per (b,h) slice ----------------
// Q/K/V global layout: [4096 tokens][4096], slice at col h*512, 512 wide.
// Block: 256 thr (4 waves). 64 q-rows/block (16 per wave), kv steps of 32.
// NOTE: AO may ALIAS Qg (workspace saving). Safe: block (qb,h) writes AO only
// in rows [qb*64,+64) x cols [h*512,+512) — exactly the Q region only IT reads,
// and those reads complete (consumed into LDS) before the epilogue stores.
__global__ __launch_bounds__(256, 1) void attn_fwd(
    const u16* __restrict__ Qg, const u16* __restrict__ Kg, const u16* __restrict__ Vg,
    u16* __restrict__ AO) {
  __shared__ u16 qlds[64][520];   // 66.5 KB  (pad: 1040B rows, 16B aligned, ~2-way)
  __shared__ u16 klds[32][520];   // 33.3 KB
  __shared__ u16 vtlds[512][40];  // 41.0 KB  V^T tile: [d][kv]
  __shared__ u16 plds[4][16][32]; //  4.1 KB  per-wave P scratch

  const int tid = threadIdx.x, lane = tid & 63, wid = tid >> 6;
  const int qb = blockIdx.x;           // 0..15 (q block of 64 rows)
  const int bh = blockIdx.y;           // 0..31
  const int b = bh >> 3, h = bh & 7;
  const size_t RS = 4096;
  const u16* Qb = Qg + (size_t)b * 1024 * RS + h * 512;
  const u16* Kb = Kg + (size_t)b * 1024 * RS + h * 512;
  const u16* Vb = Vg + (size_t)b * 1024 * RS + h * 512;

  // stage Q tile: 64 rows x 512 = 4096 16B-chunks
  #pragma unroll
  for (int i = 0; i < 16; i++) {
    int c = tid + i * 256;
    int row = c >> 6, col8 = (c & 63) * 8;
    *(uint4*)&qlds[row][col8] = *(const uint4*)&Qb[(size_t)(qb * 64 + row) * RS + col8];
  }

  f32x4 acc[32];
  #pragma unroll
  for (int n = 0; n < 32; n++) acc[n] = {0.f, 0.f, 0.f, 0.f};
  float mrow[4], lrow[4];
  #pragma unroll
  for (int r = 0; r < 4; r++) { mrow[r] = -1e30f; lrow[r] = 0.f; }

  const int qrow_base = qb * 64 + wid * 16 + (lane >> 4) * 4;  // + r
  const int nsteps = 2 * qb + 2;
  const float scale = 0.044194173824159216f;  // 1/sqrt(512)

  for (int s = 0; s < nsteps; s++) {
    __syncthreads();
    #pragma unroll
    for (int i = 0; i < 8; i++) {      // K: 32 rows x 64 chunks
      int c = tid + i * 256;
      int row = c >> 6, col8 = (c & 63) * 8;
      *(uint4*)&klds[row][col8] = *(const uint4*)&Kb[(size_t)(s * 32 + row) * RS + col8];
    }
    #pragma unroll
    for (int i = 0; i < 8; i++) {      // V -> transposed LDS
      int c = tid + i * 256;
      int row = c >> 6, col8 = (c & 63) * 8;
      uint4 v = *(const uint4*)&Vb[(size_t)(s * 32 + row) * RS + col8];
      union { u16 h[8]; uint4 v; } tv; tv.v = v;
      #pragma unroll
      for (int jj = 0; jj < 8; jj++) { // lane-rotated order: 8-way not 64-way conflicts
        int j = (jj + lane) & 7;
        vtlds[col8 + j][row] = tv.h[j];
      }
    }
    __syncthreads();

    // S[16 q][32 kv] per wave = Q(16x512) @ K^T
    f32x4 s0 = {0.f, 0.f, 0.f, 0.f}, s1 = {0.f, 0.f, 0.f, 0.f};
    #pragma unroll
    for (int kc = 0; kc < 16; kc++) {
      s16x8 aq  = *(const s16x8*)&qlds[wid * 16 + (lane & 15)][kc * 32 + (lane >> 4) * 8];
      s16x8 bk0 = *(const s16x8*)&klds[(lane & 15)][kc * 32 + (lane >> 4) * 8];
      s16x8 bk1 = *(const s16x8*)&klds[16 + (lane & 15)][kc * 32 + (lane >> 4) * 8];
      s0 = MFMA(aq, bk0, s0);
      s1 = MFMA(aq, bk1, s1);
    }

    // scale + causal mask; online softmax per q-row (rows r=0..3 of this lane)
    #pragma unroll
    for (int r = 0; r < 4; r++) {
      int q = qrow_base + r;
      int kv0 = s * 32 + (lane & 15);
      float v0 = (kv0      <= q) ? s0[r] * scale : -1e30f;
      float v1 = (kv0 + 16 <= q) ? s1[r] * scale : -1e30f;
      float mx = fmaxf(v0, v1);
      #pragma unroll
      for (int off = 1; off < 16; off <<= 1) mx = fmaxf(mx, __shfl_xor(mx, off, 64));
      float mnew = fmaxf(mrow[r], mx);
      float sf = __expf(mrow[r] - mnew);
      float p0 = __expf(v0 - mnew);
      float p1 = __expf(v1 - mnew);
      float sum = p0 + p1;
      #pragma unroll
      for (int off = 1; off < 16; off <<= 1) sum += __shfl_xor(sum, off, 64);
      lrow[r] = lrow[r] * sf + sum;
      mrow[r] = mnew;
      #pragma unroll
      for (int n = 0; n < 32; n++) acc[n][r] *= sf;
      int prow = (lane >> 4) * 4 + r;
      plds[wid][prow][lane & 15]      = f2bf(p0);
      plds[wid][prow][16 + (lane & 15)] = f2bf(p1);
    }

    // O[16 q][512 d] += P(16x32) @ V(32x512)   (V read via V^T tile)
    s16x8 pa = *(const s16x8*)&plds[wid][lane & 15][(lane >> 4) * 8];
    #pragma unroll
    for (int n = 0; n < 32; n++) {
      s16x8 bv = *(const s16x8*)&vtlds[n * 16 + (lane & 15)][(lane >> 4) * 8];
      acc[n] = MFMA(pa, bv, acc[n]);
    }
  }

  // epilogue: O /= l, write bf16 to AO[token][h*512 + d]
  #pragma unroll
  for (int r = 0; r < 4; r++) {
    float inv = 1.f / lrow[r];
    int trow = b * 1024 + qrow_base + r;
    #pragma unroll
    for (int n = 0; n < 32; n++)
      AO[(size_t)trow * RS + h * 512 + n * 16 + (lane & 15)] = f2bf(acc[n][r] * inv);
  }
}

// ---------------- launch ----------------
extern "C" void kernel_launch(void* const* d_in, const int* in_sizes, int n_in,
                              void* d_out, int out_size, void* d_ws, size_t ws_size,
                              hipStream_t stream) {
  const float* x  = (const float*)d_in[0];
  const float* Wq = (const float*)d_in[1];
  const float* Wk = (const float*)d_in[2];
  const float* Wv = (const float*)d_in[3];
  const float* Wu = (const float*)d_in[4];
  const float* bu = (const float*)d_in[5];
  float* out = (float*)d_out;

  const size_t T = 4096;      // b*t tokens
  const size_t E = 512;       // per-head dim (= emb)
  const size_t HE = 4096;     // h*e

  char* ws = (char*)d_ws;
  u16* xb  = (u16*)ws; ws += T * E * 2;            // [4096][512]
  u16* WqT = (u16*)ws; ws += HE * E * 2;           // [4096][512] = Wq^T
  u16* WkT = (u16*)ws; ws += HE * E * 2;
  u16* WvT = (u16*)ws; ws += HE * E * 2;
  u16* WuT = (u16*)ws; ws += E * HE * 2;           // [512][4096] = Wu^T
  u16* Qm  = (u16*)ws; ws += T * HE * 2;           // [4096][4096]
  u16* Km  = (u16*)ws; ws += T * HE * 2;
  u16* Vm  = (u16*)ws; ws += T * HE * 2;
  u16* AO  = Qm;   // AO aliases Qm — disjoint per-block regions, see attn_fwd note
                   // peak workspace: 116 MB

  // conversions
  cvt_f32_bf16<<<dim3((T * E / 8 + 255) / 256), dim3(256), 0, stream>>>(x, xb, (int)(T * E / 8));
  {
    dim3 blk(32, 8);
    transpose_cvt<<<dim3(HE / 32, E / 32), blk, 0, stream>>>(Wq, WqT, (int)E, (int)HE);
    transpose_cvt<<<dim3(HE / 32, E / 32), blk, 0, stream>>>(Wk, WkT, (int)E, (int)HE);
    transpose_cvt<<<dim3(HE / 32, E / 32), blk, 0, stream>>>(Wv, WvT, (int)E, (int)HE);
    transpose_cvt<<<dim3(E / 32, HE / 32), blk, 0, stream>>>(Wu, WuT, (int)HE, (int)E);
  }

  // QKV projections: [4096][512] @ [512][4096] -> bf16 [4096][4096]
  {
    dim3 grid(HE / 128, T / 128), blk(256);
    gemm_bt<1><<<grid, blk, 0, stream>>>(xb, WqT, Qm, nullptr, nullptr, (int)T, (int)HE, (int)E);
    gemm_bt<1><<<grid, blk, 0, stream>>>(xb, WkT, Km, nullptr, nullptr, (int)T, (int)HE, (int)E);
    gemm_bt<1><<<grid, blk, 0, stream>>>(xb, WvT, Vm, nullptr, nullptr, (int)T, (int)HE, (int)E);
  }

  // flash attention: grid (16 q-blocks, 32 bh). AO aliases Qm (safe, see kernel).
  attn_fwd<<<dim3(16, 32), dim3(256), 0, stream>>>(Qm, Km, Vm, AO);

  // output projection + bias: [4096][4096] @ [4096][512] -> fp32 out
  {
    dim3 grid(E / 128, T / 128), blk(256);
    gemm_bt<0><<<grid, blk, 0, stream>>>(AO, WuT, nullptr, out, bu, (int)T, (int)E, (int)HE);
  }
}

// Round 10
// 403.279 us; speedup vs baseline: 1.3915x; 1.3915x over previous
//
#include <hip/hip_runtime.h>

typedef __attribute__((ext_vector_type(8))) short s16x8;   // 8 bf16 (4 VGPRs)
typedef __attribute__((ext_vector_type(4))) float f32x4;   // MFMA 16x16 accumulator
typedef unsigned short u16;
typedef unsigned int u32;

#define MFMA(A, B, C) __builtin_amdgcn_mfma_f32_16x16x32_bf16(A, B, C, 0, 0, 0)

__device__ __forceinline__ u16 f2bf(float f) {
  u32 u = __builtin_bit_cast(u32, f);
  u += 0x7fffu + ((u >> 16) & 1u);   // RNE
  return (u16)(u >> 16);
}

// async global->LDS, 16B per lane. LDS dest = wave-uniform base + lane*16.
// Global source address is PER-LANE (m173 pre-swizzled-source pattern).
__device__ __forceinline__ void gl2lds16(const void* g, void* l) {
  __builtin_amdgcn_global_load_lds(
      (const __attribute__((address_space(1))) void*)g,
      (__attribute__((address_space(3))) void*)l, 16, 0, 0);
}

// ---------------- conversions ----------------

__global__ __launch_bounds__(256) void cvt_f32_bf16(const float* __restrict__ in,
                                                    u16* __restrict__ out, int n8) {
  int i = blockIdx.x * 256 + threadIdx.x;
  if (i >= n8) return;
  const float4* p = (const float4*)in + (size_t)i * 2;
  float4 a = p[0], b = p[1];
  union { u16 h[8]; uint4 v; } u;
  u.h[0] = f2bf(a.x); u.h[1] = f2bf(a.y); u.h[2] = f2bf(a.z); u.h[3] = f2bf(a.w);
  u.h[4] = f2bf(b.x); u.h[5] = f2bf(b.y); u.h[6] = f2bf(b.z); u.h[7] = f2bf(b.w);
  ((uint4*)out)[i] = u.v;
}

// in [R][C] fp32 -> out [C][R] bf16 (tiled transpose). R,C multiples of 32.
__global__ __launch_bounds__(256) void transpose_cvt(const float* __restrict__ in,
                                                     u16* __restrict__ out, int R, int C) {
  __shared__ float tile[32][33];
  int c0 = blockIdx.x * 32, r0 = blockIdx.y * 32;
  int tx = threadIdx.x, ty = threadIdx.y;
  #pragma unroll
  for (int i = ty; i < 32; i += 8)
    tile[i][tx] = in[(size_t)(r0 + i) * C + c0 + tx];
  __syncthreads();
  #pragma unroll
  for (int i = ty; i < 32; i += 8)
    out[(size_t)(c0 + i) * R + r0 + tx] = f2bf(tile[tx][i]);
}

// ---------------- GEMM: C[M][N] = A[M][K] @ Bt[N][K]^T ----------------
// 128x128 tile, BK=64, 4 waves 2x2, global_load_lds width=16 staging (m97).
template <int BF16_OUT>
__global__ __launch_bounds__(256, 2) void gemm_bt(
    const u16* __restrict__ A, const u16* __restrict__ Bt,
    u16* __restrict__ Cb, float* __restrict__ Cf, const float* __restrict__ bias,
    int M, int N, int K) {
  __shared__ u16 alds[128][64];   // 16 KB, LINEAR (row = 128B) — required by global_load_lds
  __shared__ u16 blds[128][64];   // 16 KB
  const int tid = threadIdx.x;
  const int lane = tid & 63, wid = tid >> 6;
  const int wm = (wid >> 1) * 64, wn = (wid & 1) * 64;
  const int m0 = blockIdx.y * 128, n0 = blockIdx.x * 128;

  const int srow = lane >> 3;        // 0..7
  const int scol = (lane & 7) * 8;   // 0..56

  f32x4 acc[4][4];
  #pragma unroll
  for (int m = 0; m < 4; m++)
    #pragma unroll
    for (int n = 0; n < 4; n++) acc[m][n] = {0.f, 0.f, 0.f, 0.f};

  for (int k0 = 0; k0 < K; k0 += 64) {
    __syncthreads();
    #pragma unroll
    for (int i = 0; i < 4; i++) {
      int rbase = (wid * 4 + i) * 8;             // wave-uniform LDS row base
      int grow = rbase + srow;
      gl2lds16(&A [(size_t)(m0 + grow) * K + k0 + scol], &alds[rbase][0]);
      gl2lds16(&Bt[(size_t)(n0 + grow) * K + k0 + scol], &blds[rbase][0]);
    }
    __syncthreads();
    #pragma unroll
    for (int kk = 0; kk < 2; kk++) {
      s16x8 af[4], bf[4];
      #pragma unroll
      for (int m = 0; m < 4; m++)
        af[m] = *(const s16x8*)&alds[wm + m * 16 + (lane & 15)][kk * 32 + (lane >> 4) * 8];
      #pragma unroll
      for (int n = 0; n < 4; n++)
        bf[n] = *(const s16x8*)&blds[wn + n * 16 + (lane & 15)][kk * 32 + (lane >> 4) * 8];
      #pragma unroll
      for (int m = 0; m < 4; m++)
        #pragma unroll
        for (int n = 0; n < 4; n++)
          acc[m][n] = MFMA(af[m], bf[n], acc[m][n]);
    }
  }

  #pragma unroll
  for (int m = 0; m < 4; m++)
    #pragma unroll
    for (int n = 0; n < 4; n++) {
      int col = n0 + wn + n * 16 + (lane & 15);
      #pragma unroll
      for (int r = 0; r < 4; r++) {
        int row = m0 + wm + m * 16 + (lane >> 4) * 4 + r;
        float v = acc[m][n][r];
        if (BF16_OUT) Cb[(size_t)row * N + col] = f2bf(v);
        else          Cf[(size_t)row * N + col] = v + bias[col];
      }
    }
}

// ---------------- Flash attention v2 (causal), per (b,h) slice ----------------
// Swapped QK^T: S^T = mfma(K, Q) -> lane owns 8 kv of ONE q (softmax = 4 shfl).
// Q in registers (64 VGPR). K and V^T in XOR-swizzled LDS via pre-swizzled-
// source global_load_lds (m173). V^T comes pre-transposed from global.
// LDS 69 KB -> 2 blocks/CU. AO may alias Q (disjoint per-block regions; Q is
// fully consumed into registers before the epilogue writes).
__global__ __launch_bounds__(256, 2) void attn_fwd(
    const u16* __restrict__ Qg, const u16* __restrict__ Kg, const u16* __restrict__ VTg,
    u16* __restrict__ AO) {
  __shared__ u16 klds[32][512];   // 32 KB; chunk c of row R holds global chunk c^(R&7)
  __shared__ u16 vt[512][32];     // 32 KB; chunk g stored at slot g^((g>>3)&3)
  __shared__ u16 plds[4][16][40]; //  5 KB; per-wave P^T->P staging

  const int tid = threadIdx.x, lane = tid & 63, w = tid >> 6;
  const int l15 = lane & 15, l16 = lane >> 4;

  // block mapping: pair qb=k with qb=15-k across the two grid halves (load balance)
  int idx = blockIdx.x;
  int half = idx >> 8, rr_ = idx & 255;
  const int bh = rr_ & 31;
  int qb = rr_ >> 5;             // 0..7
  if (half) qb = 15 - qb;        // 8..15
  const int b = bh >> 3, h = bh & 7;

  const size_t RS = 4096;
  const u16* Qb  = Qg  + ((size_t)b * 1024) * RS + h * 512;
  const u16* Kb  = Kg  + ((size_t)b * 1024) * RS + h * 512;
  const u16* VTb = VTg + ((size_t)h * 512) * RS + b * 1024;

  // Q -> registers: wave w owns q rows qb*64 + w*16 .. +16 (lane's row = +l15)
  const int qrow = qb * 64 + w * 16 + l15;   // also this lane's softmax q (S^T col)
  s16x8 aq[16];
  #pragma unroll
  for (int kc = 0; kc < 16; kc++)
    aq[kc] = *(const s16x8*)&Qb[(size_t)qrow * RS + kc * 32 + l16 * 8];

  f32x4 acc[32];
  #pragma unroll
  for (int n = 0; n < 32; n++) acc[n] = {0.f, 0.f, 0.f, 0.f};
  float m = -1e30f, lsum = 0.f;

  const int nsteps = 2 * qb + 2;
  const float scale = 0.044194173824159216f;  // 1/sqrt(512)

  for (int s = 0; s < nsteps; s++) {
    __syncthreads();   // prior-step LDS reads complete before overwrite
    // stage K tile [32 kv][512 d]: wave w rows 8w..8w+8, 1 KB/issue, source
    // chunk = lane^(R&7) so swizzled READ below sees global chunk kc*4+l16.
    #pragma unroll
    for (int i = 0; i < 8; i++) {
      int R = w * 8 + i;
      gl2lds16(&Kb[(size_t)(s * 32 + R) * RS + (size_t)((lane ^ (R & 7)) * 8)],
               &klds[R][0]);
    }
    // stage V^T tile [512 d][32 kv]: wave w issues 8; 16 rows x 64B per issue.
    // slot g^((g>>3)&3) holds global chunk g  ->  source chunk (l&3)^((l>>3)&3)
    #pragma unroll
    for (int i = 0; i < 8; i++) {
      int vr0 = (w * 8 + i) * 16;
      gl2lds16(&VTb[(size_t)(vr0 + (lane >> 2)) * RS + s * 32
                    + (size_t)(((lane & 3) ^ ((lane >> 3) & 3)) * 8)],
               &vt[vr0][0]);
    }
    __syncthreads();   // vmcnt drained -> staging visible

    // S^T[kv=32][q=16] = K·Q^T : D[row=kv=(l>>4)*4+r (+16/tile)][col=q=l15]
    f32x4 s0 = {0.f, 0.f, 0.f, 0.f}, s1 = {0.f, 0.f, 0.f, 0.f};
    #pragma unroll
    for (int kc = 0; kc < 16; kc++) {
      int ch = ((kc * 4 + l16) ^ (l15 & 7)) * 8;   // (16+l15)&7 == l15&7
      s16x8 bk0 = *(const s16x8*)&klds[l15][ch];
      s16x8 bk1 = *(const s16x8*)&klds[16 + l15][ch];
      s0 = MFMA(bk0, aq[kc], s0);
      s1 = MFMA(bk1, aq[kc], s1);
    }

    // mask + online softmax: per lane, 8 kv values of q=qrow
    float p[8];
    float pmax = -1e30f;
    #pragma unroll
    for (int r = 0; r < 4; r++) {
      int kv0 = s * 32 + l16 * 4 + r;
      float v0 = (kv0      <= qrow) ? s0[r] * scale : -1e30f;
      float v1 = (kv0 + 16 <= qrow) ? s1[r] * scale : -1e30f;
      p[r] = v0; p[4 + r] = v1;
      pmax = fmaxf(pmax, fmaxf(v0, v1));
    }
    pmax = fmaxf(pmax, __shfl_xor(pmax, 16));
    pmax = fmaxf(pmax, __shfl_xor(pmax, 32));

    // defer-max (T13, THR=8): skip O-rescale while max growth is small
    int need = __any(pmax > m + 8.f);
    float sf = 1.f;
    if (need) {
      float mnew = fmaxf(m, pmax);
      sf = __expf(m - mnew);
      m = mnew;
    }
    float psum = 0.f;
    #pragma unroll
    for (int j = 0; j < 8; j++) { p[j] = __expf(p[j] - m); psum += p[j]; }
    psum += __shfl_xor(psum, 16);
    psum += __shfl_xor(psum, 32);
    lsum = lsum * sf + psum;

    if (need) {
      float sfr[4];
      #pragma unroll
      for (int r = 0; r < 4; r++) sfr[r] = __shfl(sf, l16 * 4 + r);
      #pragma unroll
      for (int n = 0; n < 32; n++)
        #pragma unroll
        for (int r = 0; r < 4; r++) acc[n][r] *= sfr[r];
    }

    // P^T(lane-local) -> plds as [q][kv]; then PV: D[q][dv] += P[q][kv]·V^T[dv][kv]
    #pragma unroll
    for (int r = 0; r < 4; r++) {
      plds[w][l15][l16 * 4 + r]      = f2bf(p[r]);
      plds[w][l15][16 + l16 * 4 + r] = f2bf(p[4 + r]);
    }
    s16x8 pa = *(const s16x8*)&plds[w][l15][l16 * 8];
    #pragma unroll
    for (int n = 0; n < 32; n++) {
      s16x8 bv = *(const s16x8*)&vt[n * 16 + l15][(l16 ^ ((l15 >> 1) & 3)) * 8];
      acc[n] = MFMA(pa, bv, acc[n]);
    }
  }

  // epilogue: acc row q = 4*l16+r needs lsum held by lane (4*l16+r)
  float linv[4];
  #pragma unroll
  for (int r = 0; r < 4; r++) linv[r] = 1.f / __shfl(lsum, l16 * 4 + r);
  #pragma unroll
  for (int n = 0; n < 32; n++)
    #pragma unroll
    for (int r = 0; r < 4; r++) {
      int trow = b * 1024 + qb * 64 + w * 16 + l16 * 4 + r;
      AO[(size_t)trow * RS + h * 512 + n * 16 + l15] = f2bf(acc[n][r] * linv[r]);
    }
}

// ---------------- launch ----------------
extern "C" void kernel_launch(void* const* d_in, const int* in_sizes, int n_in,
                              void* d_out, int out_size, void* d_ws, size_t ws_size,
                              hipStream_t stream) {
  const float* x  = (const float*)d_in[0];
  const float* Wq = (const float*)d_in[1];
  const float* Wk = (const float*)d_in[2];
  const float* Wv = (const float*)d_in[3];
  const float* Wu = (const float*)d_in[4];
  const float* bu = (const float*)d_in[5];
  float* out = (float*)d_out;

  const size_t T = 4096;      // b*t tokens
  const size_t E = 512;       // per-head dim (= emb)
  const size_t HE = 4096;     // h*e

  char* ws = (char*)d_ws;
  u16* xb  = (u16*)ws; ws += T * E * 2;            // [4096][512]
  u16* WqT = (u16*)ws; ws += HE * E * 2;           // [4096][512] = Wq^T
  u16* WkT = (u16*)ws; ws += HE * E * 2;
  u16* WvT = (u16*)ws; ws += HE * E * 2;
  u16* WuT = (u16*)ws; ws += E * HE * 2;           // [512][4096] = Wu^T
  u16* Qm  = (u16*)ws; ws += T * HE * 2;           // [4096 token][4096 he]
  u16* Km  = (u16*)ws; ws += T * HE * 2;           // [4096 token][4096 he]
  u16* VTm = (u16*)ws; ws += T * HE * 2;           // [4096 he][4096 token] = V^T
  u16* AO  = Qm;   // AO aliases Qm — disjoint per-block regions (see attn_fwd)
                   // peak workspace: 116 MB

  // conversions
  cvt_f32_bf16<<<dim3((T * E / 8 + 255) / 256), dim3(256), 0, stream>>>(x, xb, (int)(T * E / 8));
  {
    dim3 blk(32, 8);
    transpose_cvt<<<dim3(HE / 32, E / 32), blk, 0, stream>>>(Wq, WqT, (int)E, (int)HE);
    transpose_cvt<<<dim3(HE / 32, E / 32), blk, 0, stream>>>(Wk, WkT, (int)E, (int)HE);
    transpose_cvt<<<dim3(HE / 32, E / 32), blk, 0, stream>>>(Wv, WvT, (int)E, (int)HE);
    transpose_cvt<<<dim3(E / 32, HE / 32), blk, 0, stream>>>(Wu, WuT, (int)HE, (int)E);
  }

  // Q,K projections: [T][E] @ [E][HE] -> [token][he]
  {
    dim3 grid(HE / 128, T / 128), blk(256);
    gemm_bt<1><<<grid, blk, 0, stream>>>(xb, WqT, Qm, nullptr, nullptr, (int)T, (int)HE, (int)E);
    gemm_bt<1><<<grid, blk, 0, stream>>>(xb, WkT, Km, nullptr, nullptr, (int)T, (int)HE, (int)E);
  }
  // V projection TRANSPOSED (free): VT[he][token] = WvT[he][e] · xb[token][e]^T
  {
    dim3 grid(T / 128, HE / 128), blk(256);
    gemm_bt<1><<<grid, blk, 0, stream>>>(WvT, xb, VTm, nullptr, nullptr, (int)HE, (int)T, (int)E);
  }

  // flash attention v2: 512 blocks (=256 CU x 2), qb pairing for balance
  attn_fwd<<<dim3(512), dim3(256), 0, stream>>>(Qm, Km, VTm, AO);

  // output projection + bias: [4096][4096] @ [4096][512] -> fp32 out
  {
    dim3 grid(E / 128, T / 128), blk(256);
    gemm_bt<0><<<grid, blk, 0, stream>>>(AO, WuT, nullptr, out, bu, (int)T, (int)E, (int)HE);
  }
}

// Round 11
// 366.213 us; speedup vs baseline: 1.5324x; 1.1012x over previous
//
#include <hip/hip_runtime.h>

typedef __attribute__((ext_vector_type(8))) short s16x8;   // 8 bf16 (4 VGPRs)
typedef __attribute__((ext_vector_type(4))) float f32x4;   // MFMA 16x16 accumulator
typedef unsigned short u16;
typedef unsigned int u32;
typedef unsigned long long u64;

#define MFMA(A, B, C) __builtin_amdgcn_mfma_f32_16x16x32_bf16(A, B, C, 0, 0, 0)

__device__ __forceinline__ u16 f2bf(float f) {
  u32 u = __builtin_bit_cast(u32, f);
  u += 0x7fffu + ((u >> 16) & 1u);   // RNE
  return (u16)(u >> 16);
}

// async global->LDS, 16B per lane. LDS dest = wave-uniform base + lane*16.
// Global source address is PER-LANE (m173 pre-swizzled-source pattern).
__device__ __forceinline__ void gl2lds16(const void* g, void* l) {
  __builtin_amdgcn_global_load_lds(
      (const __attribute__((address_space(1))) void*)g,
      (__attribute__((address_space(3))) void*)l, 16, 0, 0);
}

// ---------------- conversions ----------------

__global__ __launch_bounds__(256) void cvt_f32_bf16(const float* __restrict__ in,
                                                    u16* __restrict__ out, int n8) {
  int i = blockIdx.x * 256 + threadIdx.x;
  if (i >= n8) return;
  const float4* p = (const float4*)in + (size_t)i * 2;
  float4 a = p[0], b = p[1];
  union { u16 h[8]; uint4 v; } u;
  u.h[0] = f2bf(a.x); u.h[1] = f2bf(a.y); u.h[2] = f2bf(a.z); u.h[3] = f2bf(a.w);
  u.h[4] = f2bf(b.x); u.h[5] = f2bf(b.y); u.h[6] = f2bf(b.z); u.h[7] = f2bf(b.w);
  ((uint4*)out)[i] = u.v;
}

// in [R][C] fp32 -> out [C][R] bf16 (tiled transpose). R,C multiples of 32.
__global__ __launch_bounds__(256) void transpose_cvt(const float* __restrict__ in,
                                                     u16* __restrict__ out, int R, int C) {
  __shared__ float tile[32][33];
  int c0 = blockIdx.x * 32, r0 = blockIdx.y * 32;
  int tx = threadIdx.x, ty = threadIdx.y;
  #pragma unroll
  for (int i = ty; i < 32; i += 8)
    tile[i][tx] = in[(size_t)(r0 + i) * C + c0 + tx];
  __syncthreads();
  #pragma unroll
  for (int i = ty; i < 32; i += 8)
    out[(size_t)(c0 + i) * R + r0 + tx] = f2bf(tile[tx][i]);
}

// ---------------- GEMM: C[M][N] = A[M][K] @ Bt[N][K]^T ----------------
// 128x128 tile, BK=64, 4 waves 2x2, global_load_lds width=16 staging (m97).
template <int BF16_OUT>
__global__ __launch_bounds__(256, 2) void gemm_bt(
    const u16* __restrict__ A, const u16* __restrict__ Bt,
    u16* __restrict__ Cb, float* __restrict__ Cf, const float* __restrict__ bias,
    int M, int N, int K) {
  __shared__ u16 alds[128][64];   // 16 KB, LINEAR (row = 128B) — required by global_load_lds
  __shared__ u16 blds[128][64];   // 16 KB
  const int tid = threadIdx.x;
  const int lane = tid & 63, wid = tid >> 6;
  const int wm = (wid >> 1) * 64, wn = (wid & 1) * 64;
  const int m0 = blockIdx.y * 128, n0 = blockIdx.x * 128;

  const int srow = lane >> 3;        // 0..7
  const int scol = (lane & 7) * 8;   // 0..56

  f32x4 acc[4][4];
  #pragma unroll
  for (int m = 0; m < 4; m++)
    #pragma unroll
    for (int n = 0; n < 4; n++) acc[m][n] = {0.f, 0.f, 0.f, 0.f};

  for (int k0 = 0; k0 < K; k0 += 64) {
    __syncthreads();
    #pragma unroll
    for (int i = 0; i < 4; i++) {
      int rbase = (wid * 4 + i) * 8;             // wave-uniform LDS row base
      int grow = rbase + srow;
      gl2lds16(&A [(size_t)(m0 + grow) * K + k0 + scol], &alds[rbase][0]);
      gl2lds16(&Bt[(size_t)(n0 + grow) * K + k0 + scol], &blds[rbase][0]);
    }
    __syncthreads();
    #pragma unroll
    for (int kk = 0; kk < 2; kk++) {
      s16x8 af[4], bf[4];
      #pragma unroll
      for (int m = 0; m < 4; m++)
        af[m] = *(const s16x8*)&alds[wm + m * 16 + (lane & 15)][kk * 32 + (lane >> 4) * 8];
      #pragma unroll
      for (int n = 0; n < 4; n++)
        bf[n] = *(const s16x8*)&blds[wn + n * 16 + (lane & 15)][kk * 32 + (lane >> 4) * 8];
      #pragma unroll
      for (int m = 0; m < 4; m++)
        #pragma unroll
        for (int n = 0; n < 4; n++)
          acc[m][n] = MFMA(af[m], bf[n], acc[m][n]);
    }
  }

  #pragma unroll
  for (int m = 0; m < 4; m++)
    #pragma unroll
    for (int n = 0; n < 4; n++) {
      int col = n0 + wn + n * 16 + (lane & 15);
      #pragma unroll
      for (int r = 0; r < 4; r++) {
        int row = m0 + wm + m * 16 + (lane >> 4) * 4 + r;
        float v = acc[m][n][r];
        if (BF16_OUT) Cb[(size_t)row * N + col] = f2bf(v);
        else          Cf[(size_t)row * N + col] = v + bias[col];
      }
    }
}

// ---------------- Flash attention v3 (causal), per (b,h) slice ----------------
// v2 + T3 2-phase pipeline: double-buffered K/V staging issued for step s+1
// BEFORE compute of step s; ONE barrier per step (its implicit vmcnt(0) drain
// lands after compute has covered the load latency). LDS 133 KB -> 1 block/CU.
// LPT dispatch: heavy qb first, work-stealing balances (34 steps/CU avg).
// AO may alias Q: each AO region's only writer is the block that reads it as
// Q, and Q is consumed into registers before any store.
__global__ __launch_bounds__(256, 1) void attn_fwd(
    const u16* __restrict__ Qg, const u16* __restrict__ Kg, const u16* __restrict__ VTg,
    u16* __restrict__ AO) {
  __shared__ u16 klds[2][32][512]; // 64 KB; chunk c of row R holds global chunk c^(R&7)
  __shared__ u16 vt[2][512][32];   // 64 KB; chunk g stored at slot g^((g>>3)&3)
  __shared__ u16 plds[4][16][40];  //  5 KB; per-wave P^T->P staging

  const int tid = threadIdx.x, lane = tid & 63, w = tid >> 6;
  const int l15 = lane & 15, l16 = lane >> 4;

  // LPT: heavy q-blocks dispatched first
  const int qb = 15 - (blockIdx.x >> 5);   // 15..0
  const int bh = blockIdx.x & 31;
  const int b = bh >> 3, h = bh & 7;

  const size_t RS = 4096;
  const u16* Qb  = Qg  + ((size_t)b * 1024) * RS + h * 512;
  const u16* Kb  = Kg  + ((size_t)b * 1024) * RS + h * 512;
  const u16* VTb = VTg + ((size_t)h * 512) * RS + b * 1024;

  // Q -> registers: wave w owns q rows qb*64 + w*16 .. +16 (lane's row = +l15)
  const int qrow = qb * 64 + w * 16 + l15;   // also this lane's softmax q (S^T col)
  s16x8 aq[16];
  #pragma unroll
  for (int kc = 0; kc < 16; kc++)
    aq[kc] = *(const s16x8*)&Qb[(size_t)qrow * RS + kc * 32 + l16 * 8];

  const int nsteps = 2 * qb + 2;
  const float scale = 0.044194173824159216f;  // 1/sqrt(512)

  auto STAGE = [&](int s, int buf) {
    #pragma unroll
    for (int i = 0; i < 8; i++) {            // K tile [32 kv][512 d], 1 row/issue
      int R = w * 8 + i;
      gl2lds16(&Kb[(size_t)(s * 32 + R) * RS + (size_t)((lane ^ (R & 7)) * 8)],
               &klds[buf][R][0]);
    }
    #pragma unroll
    for (int i = 0; i < 8; i++) {            // V^T tile [512 d][32 kv], 16 rows/issue
      int vr0 = (w * 8 + i) * 16;
      gl2lds16(&VTb[(size_t)(vr0 + (lane >> 2)) * RS + s * 32
                    + (size_t)(((lane & 3) ^ ((lane >> 3) & 3)) * 8)],
               &vt[buf][vr0][0]);
    }
  };

  f32x4 acc[32];
  #pragma unroll
  for (int n = 0; n < 32; n++) acc[n] = {0.f, 0.f, 0.f, 0.f};
  float m = -1e30f, lsum = 0.f;

  STAGE(0, 0);
  __syncthreads();           // vmcnt(0) drained: buf0 staged
  int cur = 0;

  for (int s = 0; s < nsteps; s++) {
    if (s + 1 < nsteps) STAGE(s + 1, cur ^ 1);   // prefetch overlaps compute

    // S^T[kv=32][q=16] = K·Q^T : D[row=kv=(l>>4)*4+r (+16/tile)][col=q=l15]
    f32x4 s0 = {0.f, 0.f, 0.f, 0.f}, s1 = {0.f, 0.f, 0.f, 0.f};
    __builtin_amdgcn_s_setprio(1);
    #pragma unroll
    for (int kc = 0; kc < 16; kc++) {
      int ch = ((kc * 4 + l16) ^ (l15 & 7)) * 8;   // (16+l15)&7 == l15&7
      s16x8 bk0 = *(const s16x8*)&klds[cur][l15][ch];
      s16x8 bk1 = *(const s16x8*)&klds[cur][16 + l15][ch];
      s0 = MFMA(bk0, aq[kc], s0);
      s1 = MFMA(bk1, aq[kc], s1);
    }
    __builtin_amdgcn_s_setprio(0);

    // mask + online softmax: per lane, 8 kv values of q=qrow
    float p[8];
    float pmax = -1e30f;
    #pragma unroll
    for (int r = 0; r < 4; r++) {
      int kv0 = s * 32 + l16 * 4 + r;
      float v0 = (kv0      <= qrow) ? s0[r] * scale : -1e30f;
      float v1 = (kv0 + 16 <= qrow) ? s1[r] * scale : -1e30f;
      p[r] = v0; p[4 + r] = v1;
      pmax = fmaxf(pmax, fmaxf(v0, v1));
    }
    pmax = fmaxf(pmax, __shfl_xor(pmax, 16));
    pmax = fmaxf(pmax, __shfl_xor(pmax, 32));

    // defer-max (T13, THR=8): skip O-rescale while max growth is small
    int need = __any(pmax > m + 8.f);
    float sf = 1.f;
    if (need) {
      float mnew = fmaxf(m, pmax);
      sf = __expf(m - mnew);
      m = mnew;
    }
    float psum = 0.f;
    #pragma unroll
    for (int j = 0; j < 8; j++) { p[j] = __expf(p[j] - m); psum += p[j]; }
    psum += __shfl_xor(psum, 16);
    psum += __shfl_xor(psum, 32);
    lsum = lsum * sf + psum;

    if (need) {
      float sfr[4];
      #pragma unroll
      for (int r = 0; r < 4; r++) sfr[r] = __shfl(sf, l16 * 4 + r);
      #pragma unroll
      for (int n = 0; n < 32; n++)
        #pragma unroll
        for (int r = 0; r < 4; r++) acc[n][r] *= sfr[r];
    }

    // P^T(lane-local) -> plds as [q][kv] (packed b64 writes); then PV.
    {
      union { u16 h[4]; u64 q; } w0, w1;
      #pragma unroll
      for (int r = 0; r < 4; r++) { w0.h[r] = f2bf(p[r]); w1.h[r] = f2bf(p[4 + r]); }
      *(u64*)&plds[w][l15][l16 * 4]      = w0.q;
      *(u64*)&plds[w][l15][16 + l16 * 4] = w1.q;
    }
    s16x8 pa = *(const s16x8*)&plds[w][l15][l16 * 8];
    __builtin_amdgcn_s_setprio(1);
    #pragma unroll
    for (int n = 0; n < 32; n++) {
      s16x8 bv = *(const s16x8*)&vt[cur][n * 16 + l15][(l16 ^ ((l15 >> 1) & 3)) * 8];
      acc[n] = MFMA(pa, bv, acc[n]);
    }
    __builtin_amdgcn_s_setprio(0);

    __syncthreads();   // drain: stage(s+1) complete; all waves done with buf cur
    cur ^= 1;
  }

  // epilogue: acc row q = 4*l16+r needs lsum held by lane (4*l16+r)
  float linv[4];
  #pragma unroll
  for (int r = 0; r < 4; r++) linv[r] = 1.f / __shfl(lsum, l16 * 4 + r);
  #pragma unroll
  for (int n = 0; n < 32; n++)
    #pragma unroll
    for (int r = 0; r < 4; r++) {
      int trow = b * 1024 + qb * 64 + w * 16 + l16 * 4 + r;
      AO[(size_t)trow * RS + h * 512 + n * 16 + l15] = f2bf(acc[n][r] * linv[r]);
    }
}

// ---------------- launch ----------------
extern "C" void kernel_launch(void* const* d_in, const int* in_sizes, int n_in,
                              void* d_out, int out_size, void* d_ws, size_t ws_size,
                              hipStream_t stream) {
  const float* x  = (const float*)d_in[0];
  const float* Wq = (const float*)d_in[1];
  const float* Wk = (const float*)d_in[2];
  const float* Wv = (const float*)d_in[3];
  const float* Wu = (const float*)d_in[4];
  const float* bu = (const float*)d_in[5];
  float* out = (float*)d_out;

  const size_t T = 4096;      // b*t tokens
  const size_t E = 512;       // per-head dim (= emb)
  const size_t HE = 4096;     // h*e

  char* ws = (char*)d_ws;
  u16* xb  = (u16*)ws; ws += T * E * 2;            // [4096][512]
  u16* WqT = (u16*)ws; ws += HE * E * 2;           // [4096][512] = Wq^T
  u16* WkT = (u16*)ws; ws += HE * E * 2;
  u16* WvT = (u16*)ws; ws += HE * E * 2;
  u16* WuT = (u16*)ws; ws += E * HE * 2;           // [512][4096] = Wu^T
  u16* Qm  = (u16*)ws; ws += T * HE * 2;           // [4096 token][4096 he]
  u16* Km  = (u16*)ws; ws += T * HE * 2;           // [4096 token][4096 he]
  u16* VTm = (u16*)ws; ws += T * HE * 2;           // [4096 he][4096 token] = V^T
  u16* AO  = Qm;   // AO aliases Qm — disjoint per-block regions (see attn_fwd)
                   // peak workspace: 116 MB

  // conversions
  cvt_f32_bf16<<<dim3((T * E / 8 + 255) / 256), dim3(256), 0, stream>>>(x, xb, (int)(T * E / 8));
  {
    dim3 blk(32, 8);
    transpose_cvt<<<dim3(HE / 32, E / 32), blk, 0, stream>>>(Wq, WqT, (int)E, (int)HE);
    transpose_cvt<<<dim3(HE / 32, E / 32), blk, 0, stream>>>(Wk, WkT, (int)E, (int)HE);
    transpose_cvt<<<dim3(HE / 32, E / 32), blk, 0, stream>>>(Wv, WvT, (int)E, (int)HE);
    transpose_cvt<<<dim3(E / 32, HE / 32), blk, 0, stream>>>(Wu, WuT, (int)HE, (int)E);
  }

  // Q,K projections: [T][E] @ [E][HE] -> [token][he]
  {
    dim3 grid(HE / 128, T / 128), blk(256);
    gemm_bt<1><<<grid, blk, 0, stream>>>(xb, WqT, Qm, nullptr, nullptr, (int)T, (int)HE, (int)E);
    gemm_bt<1><<<grid, blk, 0, stream>>>(xb, WkT, Km, nullptr, nullptr, (int)T, (int)HE, (int)E);
  }
  // V projection TRANSPOSED (free): VT[he][token] = WvT[he][e] · xb[token][e]^T
  {
    dim3 grid(T / 128, HE / 128), blk(256);
    gemm_bt<1><<<grid, blk, 0, stream>>>(WvT, xb, VTm, nullptr, nullptr, (int)HE, (int)T, (int)E);
  }

  // flash attention v3: 512 blocks, 1 block/CU, LPT qb ordering
  attn_fwd<<<dim3(512), dim3(256), 0, stream>>>(Qm, Km, VTm, AO);

  // output projection + bias: [4096][4096] @ [4096][512] -> fp32 out
  {
    dim3 grid(E / 128, T / 128), blk(256);
    gemm_bt<0><<<grid, blk, 0, stream>>>(AO, WuT, nullptr, out, bu, (int)T, (int)E, (int)HE);
  }
}